// Round 2
// baseline (1077.057 us; speedup 1.0000x reference)
//
#include <hip/hip_runtime.h>
#include <cstdint>
#include <cstddef>

// ---------------------------------------------------------------------------
// Pointer-network decoder: B=128 batches decode T=32 steps over N=512 nodes.
// One block per batch (sequential dependence across steps), 1024 threads.
// Round 4: same data placement as round 3 (encT2[b] register-staged, W2T +
// 32 Wih rows in 128KB dynamic LDS) but with __launch_bounds__(1024, 4):
// the 145KB LDS footprint forces 1 block/CU (4 waves/EU) anyway, so declare
// it -> VGPR cap 64 -> 128, er[64] stays in registers instead of spilling
// to scratch (round 3: WRITE_SIZE 46MB of spill traffic, 2x regression).
// All FMA orders/accumulators unchanged -> bit-identical outputs (absmax 0).
// Sampling reproduces jax.random.categorical bit-exactly (threefry2x32).
// ---------------------------------------------------------------------------

constexpr int B = 128, N = 512, H = 128, T = 32;
constexpr int G4 = 4 * H;  // 512
constexpr float TINYF = 1.17549435e-38f;  // np.finfo(float32).tiny

// ---- JAX threefry2x32 block cipher (20 rounds) ----------------------------
__host__ __device__ inline uint32_t rotl32(uint32_t v, int d) {
  return (v << d) | (v >> (32 - d));
}

__host__ __device__ inline void tf2x32(uint32_t k0, uint32_t k1,
                                       uint32_t x0, uint32_t x1,
                                       uint32_t& o0, uint32_t& o1) {
  uint32_t ks2 = k0 ^ k1 ^ 0x1BD11BDAu;
  x0 += k0; x1 += k1;
#define TF_R(r) x0 += x1; x1 = rotl32(x1, (r)); x1 ^= x0;
  TF_R(13) TF_R(15) TF_R(26) TF_R(6)
  x0 += k1; x1 += ks2 + 1u;
  TF_R(17) TF_R(29) TF_R(16) TF_R(24)
  x0 += ks2; x1 += k0 + 2u;
  TF_R(13) TF_R(15) TF_R(26) TF_R(6)
  x0 += k0; x1 += k1 + 3u;
  TF_R(17) TF_R(29) TF_R(16) TF_R(24)
  x0 += k1; x1 += ks2 + 4u;
  TF_R(13) TF_R(15) TF_R(26) TF_R(6)
  x0 += ks2; x1 += k0 + 5u;
#undef TF_R
  o0 = x0; o1 = x1;
}

struct KeyArgs { uint32_t k[2 * T]; };  // per-step subkeys, 256 B by value

// Host-side key chain (partitionable split): key0 = (0,42);
// new_key = E_key(0,0), sub = E_key(0,1).
static KeyArgs make_subkeys() {
  KeyArgs ka;
  uint32_t k0 = 0u, k1 = 42u;
  for (int t = 0; t < T; ++t) {
    uint32_t n0, n1, s0, s1;
    tf2x32(k0, k1, 0u, 0u, n0, n1);
    tf2x32(k0, k1, 0u, 1u, s0, s1);
    ka.k[2 * t] = s0; ka.k[2 * t + 1] = s1;
    k0 = n0; k1 = n1;
  }
  return ka;
}

// 32-bit draw i (of 65536) for this step's subkey: w0^w1 of E_sub(0, i)
__device__ inline uint32_t gumbel_bits(uint32_t sk0, uint32_t sk1, int i) {
  uint32_t o0, o1;
  tf2x32(sk0, sk1, 0u, (uint32_t)i, o0, o1);
  return o0 ^ o1;
}

// fast tanh for the score hot loop; abs err ~2e-7 (clamp avoids inf/inf NaN)
__device__ inline float fast_tanh(float x) {
  float cx = fminf(9.0f, fmaxf(-9.0f, x));
  float t = __expf(2.0f * cx);
  return (t - 1.0f) * __builtin_amdgcn_rcpf(t + 1.0f);
}

// ---- setup kernel 1: transpose weights for coalesced access ---------------
__global__ void k_transpose(const float* __restrict__ Wih, const float* __restrict__ Whh,
                            const float* __restrict__ W2, const float* __restrict__ W1,
                            float* __restrict__ WihT, float* __restrict__ WhhT,
                            float* __restrict__ W2T, float* __restrict__ W1T) {
  int i = blockIdx.x * blockDim.x + threadIdx.x;
  if (i < H * G4) {
    int h = i >> 9, j = i & (G4 - 1);
    WihT[i] = Wih[j * H + h];
  } else if (i < 2 * H * G4) {
    int q = i - H * G4; int h = q >> 9, j = q & (G4 - 1);
    WhhT[q] = Whh[j * H + h];
  } else if (i < 2 * H * G4 + H * H) {
    int q = i - 2 * H * G4; int h = q >> 7, k = q & (H - 1);
    W2T[q] = W2[k * H + h];
  } else if (i < 2 * H * G4 + 2 * H * H) {
    int q = i - 2 * H * G4 - H * H; int h = q >> 7, k = q & (H - 1);
    W1T[q] = W1[k * H + h];
  }
}

// ---- setup kernel 2: encT2[b,k,n] = sum_h enc[b,n,h] * W1[k,h] ------------
// (k-major output for the decode score SGEMV). 16 enc rows staged in LDS;
// 256 threads = 128 k x 2 n-groups; per-thread 8 consecutive n -> 2x float4.
__global__ __launch_bounds__(256) void k_enc_trans(const float* __restrict__ enc,
                                                   const float* __restrict__ W1T,
                                                   float* __restrict__ encT2) {
  __shared__ __align__(16) float es[16 * 128];  // 8 KB
  int blk = blockIdx.x;
  int b = blk >> 5;               // 32 blocks per batch
  int n0 = (blk & 31) << 4;       // 16 rows
  const float* src = enc + ((size_t)b * N + n0) * H;
  for (int i = threadIdx.x; i < 16 * 128; i += 256) es[i] = src[i];
  __syncthreads();
  int k = threadIdx.x & 127, ng = threadIdx.x >> 7;
  float acc[8] = {0.f, 0.f, 0.f, 0.f, 0.f, 0.f, 0.f, 0.f};
  for (int h = 0; h < H; h += 4) {
    float w0 = W1T[(h + 0) * H + k];   // coalesced (lanes = consecutive k)
    float w1 = W1T[(h + 1) * H + k];
    float w2 = W1T[(h + 2) * H + k];
    float w3 = W1T[(h + 3) * H + k];
#pragma unroll
    for (int j = 0; j < 8; ++j) {
      const float4 e = *(const float4*)&es[(ng * 8 + j) * 128 + h];  // broadcast
      acc[j] += w0 * e.x + w1 * e.y + w2 * e.z + w3 * e.w;
    }
  }
  float* dst = encT2 + (size_t)b * H * N + (size_t)k * N + n0 + ng * 8;
  ((float4*)dst)[0] = make_float4(acc[0], acc[1], acc[2], acc[3]);
  ((float4*)dst)[1] = make_float4(acc[4], acc[5], acc[6], acc[7]);
}

// ---- main fused decoder: 1 block per batch, 1024 threads (16 waves) -------
// Dynamic LDS (128 KB): [0,16384) = W2T staged; [16384,32768) = WihT rows 0..31.
// __launch_bounds__(1024, 4): 4 waves/EU (= 1 block/CU, forced by LDS anyway)
// -> VGPR budget 128; er[64] must stay in registers (watch WRITE_SIZE for spill).
__global__ __launch_bounds__(1024, 4) void k_decode(
    const float* __restrict__ enc, const float* __restrict__ encT2,
    const float* __restrict__ WihT, const float* __restrict__ WhhT,
    const float* __restrict__ W2T,
    const float* __restrict__ bih, const float* __restrict__ bhh,
    const float* __restrict__ v,
    KeyArgs keys, float* __restrict__ out) {
  __shared__ __align__(16) float xs[H];     // dec_input
  __shared__ __align__(16) float hs[H];     // hx
  __shared__ __align__(16) float cs[H];     // cx
  __shared__ __align__(16) float dt[H];     // dec_trans = hx @ W2^T
  __shared__ __align__(16) float vv[H];
  __shared__ __align__(16) float bsum[G4];  // b_ih + b_hh
  __shared__ float pg[2][G4];               // gate partials (split-K halves)
  __shared__ float ps[2][N];                // score partials
  __shared__ float pdt[4][H];               // dt partials (and init-mean partials)
  __shared__ float sc[N];                   // masked scores for softmax
  __shared__ float wr_z[8], wr_m[8], wr_s[8];
  __shared__ int wr_i[8];
  __shared__ float s_smax;
  __shared__ int s_idx;

  extern __shared__ __align__(16) float dynlds[];
  float* w2s = dynlds;           // 16384 floats: W2T[h][k], h-major
  float* wis = dynlds + 16384;   // 16384 floats: WihT rows 0..31

  const int tid = threadIdx.x;
  const int b = blockIdx.x;
  const int lane = tid & 63;
  const int wave = tid >> 6;
  const int half = tid >> 9;     // 0/1: split-K half
  const int id = tid & 511;

  // ---- register-stage encT2[b][kb+kk][n] for this thread's (n, k-range) ---
  // (exactly the values P4 streamed per step in round 2; read ONCE here)
  float er[64];
  {
    const int kb = half * 64;
    const float* ep = encT2 + (size_t)b * (H * N) + (size_t)kb * N + id;
#pragma unroll
    for (int kk = 0; kk < 64; ++kk) er[kk] = ep[(size_t)kk * N];
  }

  // ---- stage W2T (64KB) + WihT rows [0,32) (64KB) into dynamic LDS --------
  {
    const float4* s2 = (const float4*)W2T;
    const float4* si = (const float4*)WihT;
    float4* d2 = (float4*)w2s;
    float4* di = (float4*)wis;
#pragma unroll
    for (int i = 0; i < 4; ++i) {
      d2[tid + i * 1024] = s2[tid + i * 1024];
      di[tid + i * 1024] = si[tid + i * 1024];
    }
  }

  // ---- init: dec_input = mean_n enc[b,n,:]; h = c = 0 ----
  if (tid < 512) {
    int h = tid & 127, part = tid >> 7;
    float s = 0.f;
    const float* p = enc + ((size_t)b * N + part * 128) * H + h;
#pragma unroll 8
    for (int n = 0; n < 128; ++n) s += p[(size_t)n * H];  // coalesced across h
    pdt[part][h] = s;
    bsum[tid] = bih[tid] + bhh[tid];
  }
  if (tid < 128) { hs[tid] = 0.f; cs[tid] = 0.f; vv[tid] = v[tid]; }
  __syncthreads();
  if (tid < 128)
    xs[tid] = (pdt[0][tid] + pdt[1][tid] + pdt[2][tid] + pdt[3][tid]) * (1.0f / N);
  bool masked = false;  // thread id owns node id (tid<512)
  __syncthreads();

  for (int t = 0; t < T; ++t) {
    // --- P1: gate partials: j = id, h-range = half*64..+63 ------------------
    // a0/a1 kept as separate ascending-h accumulators -> bitwise == round 2.
    {
      const int hb = half * 64;
      float a0 = 0.f, a1 = 0.f;
      if (half == 0) {
        // h 0..31 from LDS-staged Wih rows
#pragma unroll 8
        for (int h = 0; h < 32; h += 4) {
          const float4 xv = *(const float4*)&xs[h];
          a0 += wis[(h + 0) * G4 + id] * xv.x;
          a0 += wis[(h + 1) * G4 + id] * xv.y;
          a0 += wis[(h + 2) * G4 + id] * xv.z;
          a0 += wis[(h + 3) * G4 + id] * xv.w;
        }
        const float* wi = WihT + (size_t)32 * G4 + id;
#pragma unroll 8
        for (int h = 0; h < 32; h += 4) {
          const float4 xv = *(const float4*)&xs[32 + h];
          a0 += wi[(h + 0) * G4] * xv.x;
          a0 += wi[(h + 1) * G4] * xv.y;
          a0 += wi[(h + 2) * G4] * xv.z;
          a0 += wi[(h + 3) * G4] * xv.w;
        }
      } else {
        const float* wi = WihT + (size_t)64 * G4 + id;
#pragma unroll 8
        for (int h = 0; h < 64; h += 4) {
          const float4 xv = *(const float4*)&xs[64 + h];
          a0 += wi[(h + 0) * G4] * xv.x;
          a0 += wi[(h + 1) * G4] * xv.y;
          a0 += wi[(h + 2) * G4] * xv.z;
          a0 += wi[(h + 3) * G4] * xv.w;
        }
      }
      {
        const float* wh = WhhT + (size_t)hb * G4 + id;
#pragma unroll 8
        for (int h = 0; h < 64; h += 4) {
          const float4 hv = *(const float4*)&hs[hb + h];
          a1 += wh[(h + 0) * G4] * hv.x;
          a1 += wh[(h + 1) * G4] * hv.y;
          a1 += wh[(h + 2) * G4] * hv.z;
          a1 += wh[(h + 3) * G4] * hv.w;
        }
      }
      pg[half][id] = a0 + a1;
    }
    __syncthreads();
    // --- P2: cell update (torch gate order i,f,g,o) -------------------------
    if (tid < 128) {
      float gi = pg[0][tid] + pg[1][tid] + bsum[tid];
      float gf = pg[0][H + tid] + pg[1][H + tid] + bsum[H + tid];
      float gg = pg[0][2 * H + tid] + pg[1][2 * H + tid] + bsum[2 * H + tid];
      float go = pg[0][3 * H + tid] + pg[1][3 * H + tid] + bsum[3 * H + tid];
      gi = 1.0f / (1.0f + expf(-gi));
      gf = 1.0f / (1.0f + expf(-gf));
      gg = tanhf(gg);
      go = 1.0f / (1.0f + expf(-go));
      float c = gf * cs[tid] + gi * gg;
      cs[tid] = c;
      hs[tid] = go * tanhf(c);
    }
    __syncthreads();
    // --- P3: dt partials from LDS-staged W2T: k = tid&127, 32 h each --------
    if (tid < 512) {
      int k = tid & 127, part = tid >> 7;
      const int hbp = part * 32;
      float a = 0.f;
#pragma unroll 8
      for (int h = 0; h < 32; h += 4) {
        const float4 hv = *(const float4*)&hs[hbp + h];
        a += w2s[(hbp + h + 0) * H + k] * hv.x;
        a += w2s[(hbp + h + 1) * H + k] * hv.y;
        a += w2s[(hbp + h + 2) * H + k] * hv.z;
        a += w2s[(hbp + h + 3) * H + k] * hv.w;
      }
      pdt[part][k] = a;
    }
    __syncthreads();
    if (tid < 128) dt[tid] = pdt[0][tid] + pdt[1][tid] + pdt[2][tid] + pdt[3][tid];
    __syncthreads();
    // --- P4: score partials from REGISTERS: thread n = id, k = half*64..+63 -
    // er[kk] == encT2[b][kb+kk][n]; dt/vv broadcast via float4; accumulator
    // assignment (a0 = even k, a1 = odd k, ascending) bitwise == round 2.
    {
      const int kb = half * 64;
      float a0 = 0.f, a1 = 0.f;
#pragma unroll
      for (int k4 = 0; k4 < 64; k4 += 4) {
        const float4 dv = *(const float4*)&dt[kb + k4];
        const float4 vw = *(const float4*)&vv[kb + k4];
        a0 += vw.x * fast_tanh(er[k4 + 0] + dv.x);
        a1 += vw.y * fast_tanh(er[k4 + 1] + dv.y);
        a0 += vw.z * fast_tanh(er[k4 + 2] + dv.z);
        a1 += vw.w * fast_tanh(er[k4 + 3] + dv.w);
      }
      ps[half][id] = a0 + a1;
    }
    __syncthreads();
    // --- P5a: mask, gumbel, per-wave argmax + score max (waves 0..7) --------
    if (tid < 512) {
      float s = masked ? -INFINITY : (ps[0][tid] + ps[1][tid]);
      sc[tid] = s;
      uint32_t bits = gumbel_bits(keys.k[2 * t], keys.k[2 * t + 1], b * N + tid);
      // XLA uniform(minval=tiny, maxval=1): bits->[1,2)->-1, +tiny, max
      float f = __uint_as_float((bits >> 9) | 0x3f800000u) - 1.0f;
      float u = fmaxf(TINYF, f + TINYF);
      float g = -logf(-logf(u));  // accurate logf (hw log2 too sloppy near u~1)
      float z = s + g;
      int zi = tid;
      float m = s;
#pragma unroll
      for (int d = 32; d >= 1; d >>= 1) {
        float oz = __shfl_xor(z, d);
        int oi = __shfl_xor(zi, d);
        float om = __shfl_xor(m, d);
        if (oz > z || (oz == z && oi < zi)) { z = oz; zi = oi; }  // first-idx ties
        m = fmaxf(m, om);
      }
      if (lane == 0) { wr_z[wave] = z; wr_i[wave] = zi; wr_m[wave] = m; }
    }
    __syncthreads();
    // --- P5b: final argmax + max over the 8 waves ---------------------------
    if (tid == 0) {
      float bz = wr_z[0]; int bi = wr_i[0]; float bm = wr_m[0];
#pragma unroll
      for (int w = 1; w < 8; ++w) {
        if (wr_z[w] > bz || (wr_z[w] == bz && wr_i[w] < bi)) { bz = wr_z[w]; bi = wr_i[w]; }
        bm = fmaxf(bm, wr_m[w]);
      }
      s_idx = bi; s_smax = bm;
    }
    __syncthreads();
    // --- P6: softmax denom; mask update; next dec_input ---------------------
    if (tid < 512) {
      float e = expf(sc[tid] - s_smax);  // masked: exp(-inf) = 0
#pragma unroll
      for (int d = 32; d >= 1; d >>= 1) e += __shfl_xor(e, d);
      if (lane == 0) wr_s[wave] = e;
      if (tid == s_idx) masked = true;
    } else if (tid < 640) {
      xs[tid - 512] = enc[((size_t)b * N + s_idx) * H + (tid - 512)];
    }
    __syncthreads();
    // --- P6b: outputs (no barrier needed: writes global only) ---------------
    if (tid == 0) {
      float sum = wr_s[0] + wr_s[1] + wr_s[2] + wr_s[3]
                + wr_s[4] + wr_s[5] + wr_s[6] + wr_s[7];
      float p = expf(sc[s_idx] - s_smax) / sum;
      out[(size_t)b * T + t] = (float)s_idx;                       // tours [B,T]
      out[(size_t)B * T + (size_t)b * T + t] = logf(p + 1e-9f);    // log_probs
    }
    __syncthreads();
  }
}

// ---------------------------------------------------------------------------
extern "C" void kernel_launch(void* const* d_in, const int* in_sizes, int n_in,
                              void* d_out, int out_size, void* d_ws, size_t ws_size,
                              hipStream_t stream) {
  (void)in_sizes; (void)n_in; (void)out_size; (void)ws_size;
  const float* enc = (const float*)d_in[0];
  const float* Wih = (const float*)d_in[1];
  const float* Whh = (const float*)d_in[2];
  const float* bih = (const float*)d_in[3];
  const float* bhh = (const float*)d_in[4];
  const float* W1  = (const float*)d_in[5];
  const float* W2  = (const float*)d_in[6];
  const float* v   = (const float*)d_in[7];
  float* out = (float*)d_out;
  float* ws = (float*)d_ws;

  // ws layout (floats): WihT 65536 | WhhT 65536 | W2T 16384 | W1T 16384 | encT2 8388608
  float* WihT  = ws;
  float* WhhT  = ws + 65536;
  float* W2T   = ws + 131072;
  float* W1T   = ws + 147456;
  float* encT2 = ws + 163840;   // [b][k][n], ~33.5 MB

  KeyArgs keys = make_subkeys();  // pure host arithmetic: capture-safe

  // allow 128KB dynamic LDS for k_decode (host-side attr; capture-safe)
  static bool lds_attr_set = false;
  if (!lds_attr_set) {
    (void)hipFuncSetAttribute(reinterpret_cast<const void*>(k_decode),
                              hipFuncAttributeMaxDynamicSharedMemorySize, 131072);
    lds_attr_set = true;
  }

  k_transpose<<<640, 256, 0, stream>>>(Wih, Whh, W2, W1, WihT, WhhT, W2T, W1T);
  k_enc_trans<<<B * N / 16, 256, 0, stream>>>(enc, W1T, encT2);
  k_decode<<<B, 1024, 131072, stream>>>(enc, encT2, WihT, WhhT, W2T, bih, bhh, v, keys, out);
}

// Round 3
// 1037.949 us; speedup vs baseline: 1.0377x; 1.0377x over previous
//
#include <hip/hip_runtime.h>
#include <cstdint>
#include <cstddef>

// ---------------------------------------------------------------------------
// Pointer-network decoder: B=128 batches decode T=32 steps over N=512 nodes.
// One block per batch (sequential dependence across steps), 1024 threads.
// Round 5: identical placement to round 3/4 (encT2[b] register-staged as
// er[64]; W2T + 32 Wih rows in 128KB dynamic LDS). Fix for the persistent
// er-spill (WRITE_SIZE 46MB, VGPR stuck at 64): the __launch_bounds__ 2nd
// arg was NOT honored (round 4 A/B: identical codegen), so the register
// budget stayed 512/8=64. Use the clang-native
// __attribute__((amdgpu_waves_per_eu(4,4))) instead -> budget 512/4 = 128
// VGPRs/wave; 16-wave block still launches (4 waves/SIMD x 128 = full file)
// and the 145KB LDS footprint forces 1 block/CU anyway.
// All FMA orders/accumulators unchanged -> bit-identical outputs (absmax 0).
// Sampling reproduces jax.random.categorical bit-exactly (threefry2x32).
// ---------------------------------------------------------------------------

constexpr int B = 128, N = 512, H = 128, T = 32;
constexpr int G4 = 4 * H;  // 512
constexpr float TINYF = 1.17549435e-38f;  // np.finfo(float32).tiny

// ---- JAX threefry2x32 block cipher (20 rounds) ----------------------------
__host__ __device__ inline uint32_t rotl32(uint32_t v, int d) {
  return (v << d) | (v >> (32 - d));
}

__host__ __device__ inline void tf2x32(uint32_t k0, uint32_t k1,
                                       uint32_t x0, uint32_t x1,
                                       uint32_t& o0, uint32_t& o1) {
  uint32_t ks2 = k0 ^ k1 ^ 0x1BD11BDAu;
  x0 += k0; x1 += k1;
#define TF_R(r) x0 += x1; x1 = rotl32(x1, (r)); x1 ^= x0;
  TF_R(13) TF_R(15) TF_R(26) TF_R(6)
  x0 += k1; x1 += ks2 + 1u;
  TF_R(17) TF_R(29) TF_R(16) TF_R(24)
  x0 += ks2; x1 += k0 + 2u;
  TF_R(13) TF_R(15) TF_R(26) TF_R(6)
  x0 += k0; x1 += k1 + 3u;
  TF_R(17) TF_R(29) TF_R(16) TF_R(24)
  x0 += k1; x1 += ks2 + 4u;
  TF_R(13) TF_R(15) TF_R(26) TF_R(6)
  x0 += ks2; x1 += k0 + 5u;
#undef TF_R
  o0 = x0; o1 = x1;
}

struct KeyArgs { uint32_t k[2 * T]; };  // per-step subkeys, 256 B by value

// Host-side key chain (partitionable split): key0 = (0,42);
// new_key = E_key(0,0), sub = E_key(0,1).
static KeyArgs make_subkeys() {
  KeyArgs ka;
  uint32_t k0 = 0u, k1 = 42u;
  for (int t = 0; t < T; ++t) {
    uint32_t n0, n1, s0, s1;
    tf2x32(k0, k1, 0u, 0u, n0, n1);
    tf2x32(k0, k1, 0u, 1u, s0, s1);
    ka.k[2 * t] = s0; ka.k[2 * t + 1] = s1;
    k0 = n0; k1 = n1;
  }
  return ka;
}

// 32-bit draw i (of 65536) for this step's subkey: w0^w1 of E_sub(0, i)
__device__ inline uint32_t gumbel_bits(uint32_t sk0, uint32_t sk1, int i) {
  uint32_t o0, o1;
  tf2x32(sk0, sk1, 0u, (uint32_t)i, o0, o1);
  return o0 ^ o1;
}

// fast tanh for the score hot loop; abs err ~2e-7 (clamp avoids inf/inf NaN)
__device__ inline float fast_tanh(float x) {
  float cx = fminf(9.0f, fmaxf(-9.0f, x));
  float t = __expf(2.0f * cx);
  return (t - 1.0f) * __builtin_amdgcn_rcpf(t + 1.0f);
}

// ---- setup kernel 1: transpose weights for coalesced access ---------------
__global__ void k_transpose(const float* __restrict__ Wih, const float* __restrict__ Whh,
                            const float* __restrict__ W2, const float* __restrict__ W1,
                            float* __restrict__ WihT, float* __restrict__ WhhT,
                            float* __restrict__ W2T, float* __restrict__ W1T) {
  int i = blockIdx.x * blockDim.x + threadIdx.x;
  if (i < H * G4) {
    int h = i >> 9, j = i & (G4 - 1);
    WihT[i] = Wih[j * H + h];
  } else if (i < 2 * H * G4) {
    int q = i - H * G4; int h = q >> 9, j = q & (G4 - 1);
    WhhT[q] = Whh[j * H + h];
  } else if (i < 2 * H * G4 + H * H) {
    int q = i - 2 * H * G4; int h = q >> 7, k = q & (H - 1);
    W2T[q] = W2[k * H + h];
  } else if (i < 2 * H * G4 + 2 * H * H) {
    int q = i - 2 * H * G4 - H * H; int h = q >> 7, k = q & (H - 1);
    W1T[q] = W1[k * H + h];
  }
}

// ---- setup kernel 2: encT2[b,k,n] = sum_h enc[b,n,h] * W1[k,h] ------------
// (k-major output for the decode score SGEMV). 16 enc rows staged in LDS;
// 256 threads = 128 k x 2 n-groups; per-thread 8 consecutive n -> 2x float4.
__global__ __launch_bounds__(256) void k_enc_trans(const float* __restrict__ enc,
                                                   const float* __restrict__ W1T,
                                                   float* __restrict__ encT2) {
  __shared__ __align__(16) float es[16 * 128];  // 8 KB
  int blk = blockIdx.x;
  int b = blk >> 5;               // 32 blocks per batch
  int n0 = (blk & 31) << 4;       // 16 rows
  const float* src = enc + ((size_t)b * N + n0) * H;
  for (int i = threadIdx.x; i < 16 * 128; i += 256) es[i] = src[i];
  __syncthreads();
  int k = threadIdx.x & 127, ng = threadIdx.x >> 7;
  float acc[8] = {0.f, 0.f, 0.f, 0.f, 0.f, 0.f, 0.f, 0.f};
  for (int h = 0; h < H; h += 4) {
    float w0 = W1T[(h + 0) * H + k];   // coalesced (lanes = consecutive k)
    float w1 = W1T[(h + 1) * H + k];
    float w2 = W1T[(h + 2) * H + k];
    float w3 = W1T[(h + 3) * H + k];
#pragma unroll
    for (int j = 0; j < 8; ++j) {
      const float4 e = *(const float4*)&es[(ng * 8 + j) * 128 + h];  // broadcast
      acc[j] += w0 * e.x + w1 * e.y + w2 * e.z + w3 * e.w;
    }
  }
  float* dst = encT2 + (size_t)b * H * N + (size_t)k * N + n0 + ng * 8;
  ((float4*)dst)[0] = make_float4(acc[0], acc[1], acc[2], acc[3]);
  ((float4*)dst)[1] = make_float4(acc[4], acc[5], acc[6], acc[7]);
}

// ---- main fused decoder: 1 block per batch, 1024 threads (16 waves) -------
// Dynamic LDS (128 KB): [0,16384) = W2T staged; [16384,32768) = WihT rows 0..31.
// amdgpu_waves_per_eu(4,4): VGPR budget 128/wave (4 waves/SIMD = 1 block/CU,
// which the 145KB LDS footprint forces anyway). er[64] must stay in registers
// -- verify via VGPR_Count ~112 and WRITE_SIZE ~0.3MB (no spill).
__global__ __launch_bounds__(1024)
__attribute__((amdgpu_waves_per_eu(4, 4))) void k_decode(
    const float* __restrict__ enc, const float* __restrict__ encT2,
    const float* __restrict__ WihT, const float* __restrict__ WhhT,
    const float* __restrict__ W2T,
    const float* __restrict__ bih, const float* __restrict__ bhh,
    const float* __restrict__ v,
    KeyArgs keys, float* __restrict__ out) {
  __shared__ __align__(16) float xs[H];     // dec_input
  __shared__ __align__(16) float hs[H];     // hx
  __shared__ __align__(16) float cs[H];     // cx
  __shared__ __align__(16) float dt[H];     // dec_trans = hx @ W2^T
  __shared__ __align__(16) float vv[H];
  __shared__ __align__(16) float bsum[G4];  // b_ih + b_hh
  __shared__ float pg[2][G4];               // gate partials (split-K halves)
  __shared__ float ps[2][N];                // score partials
  __shared__ float pdt[4][H];               // dt partials (and init-mean partials)
  __shared__ float sc[N];                   // masked scores for softmax
  __shared__ float wr_z[8], wr_m[8], wr_s[8];
  __shared__ int wr_i[8];
  __shared__ float s_smax;
  __shared__ int s_idx;

  extern __shared__ __align__(16) float dynlds[];
  float* w2s = dynlds;           // 16384 floats: W2T[h][k], h-major
  float* wis = dynlds + 16384;   // 16384 floats: WihT rows 0..31

  const int tid = threadIdx.x;
  const int b = blockIdx.x;
  const int lane = tid & 63;
  const int wave = tid >> 6;
  const int half = tid >> 9;     // 0/1: split-K half
  const int id = tid & 511;

  // ---- register-stage encT2[b][kb+kk][n] for this thread's (n, k-range) ---
  // (exactly the values P4 streamed per step in round 2; read ONCE here)
  float er[64];
  {
    const int kb = half * 64;
    const float* ep = encT2 + (size_t)b * (H * N) + (size_t)kb * N + id;
#pragma unroll
    for (int kk = 0; kk < 64; ++kk) er[kk] = ep[(size_t)kk * N];
  }

  // ---- stage W2T (64KB) + WihT rows [0,32) (64KB) into dynamic LDS --------
  {
    const float4* s2 = (const float4*)W2T;
    const float4* si = (const float4*)WihT;
    float4* d2 = (float4*)w2s;
    float4* di = (float4*)wis;
#pragma unroll
    for (int i = 0; i < 4; ++i) {
      d2[tid + i * 1024] = s2[tid + i * 1024];
      di[tid + i * 1024] = si[tid + i * 1024];
    }
  }

  // ---- init: dec_input = mean_n enc[b,n,:]; h = c = 0 ----
  if (tid < 512) {
    int h = tid & 127, part = tid >> 7;
    float s = 0.f;
    const float* p = enc + ((size_t)b * N + part * 128) * H + h;
#pragma unroll 8
    for (int n = 0; n < 128; ++n) s += p[(size_t)n * H];  // coalesced across h
    pdt[part][h] = s;
    bsum[tid] = bih[tid] + bhh[tid];
  }
  if (tid < 128) { hs[tid] = 0.f; cs[tid] = 0.f; vv[tid] = v[tid]; }
  __syncthreads();
  if (tid < 128)
    xs[tid] = (pdt[0][tid] + pdt[1][tid] + pdt[2][tid] + pdt[3][tid]) * (1.0f / N);
  bool masked = false;  // thread id owns node id (tid<512)
  __syncthreads();

  for (int t = 0; t < T; ++t) {
    // --- P1: gate partials: j = id, h-range = half*64..+63 ------------------
    // a0/a1 kept as separate ascending-h accumulators -> bitwise == round 2.
    {
      const int hb = half * 64;
      float a0 = 0.f, a1 = 0.f;
      if (half == 0) {
        // h 0..31 from LDS-staged Wih rows
#pragma unroll 8
        for (int h = 0; h < 32; h += 4) {
          const float4 xv = *(const float4*)&xs[h];
          a0 += wis[(h + 0) * G4 + id] * xv.x;
          a0 += wis[(h + 1) * G4 + id] * xv.y;
          a0 += wis[(h + 2) * G4 + id] * xv.z;
          a0 += wis[(h + 3) * G4 + id] * xv.w;
        }
        const float* wi = WihT + (size_t)32 * G4 + id;
#pragma unroll 8
        for (int h = 0; h < 32; h += 4) {
          const float4 xv = *(const float4*)&xs[32 + h];
          a0 += wi[(h + 0) * G4] * xv.x;
          a0 += wi[(h + 1) * G4] * xv.y;
          a0 += wi[(h + 2) * G4] * xv.z;
          a0 += wi[(h + 3) * G4] * xv.w;
        }
      } else {
        const float* wi = WihT + (size_t)64 * G4 + id;
#pragma unroll 8
        for (int h = 0; h < 64; h += 4) {
          const float4 xv = *(const float4*)&xs[64 + h];
          a0 += wi[(h + 0) * G4] * xv.x;
          a0 += wi[(h + 1) * G4] * xv.y;
          a0 += wi[(h + 2) * G4] * xv.z;
          a0 += wi[(h + 3) * G4] * xv.w;
        }
      }
      {
        const float* wh = WhhT + (size_t)hb * G4 + id;
#pragma unroll 8
        for (int h = 0; h < 64; h += 4) {
          const float4 hv = *(const float4*)&hs[hb + h];
          a1 += wh[(h + 0) * G4] * hv.x;
          a1 += wh[(h + 1) * G4] * hv.y;
          a1 += wh[(h + 2) * G4] * hv.z;
          a1 += wh[(h + 3) * G4] * hv.w;
        }
      }
      pg[half][id] = a0 + a1;
    }
    __syncthreads();
    // --- P2: cell update (torch gate order i,f,g,o) -------------------------
    if (tid < 128) {
      float gi = pg[0][tid] + pg[1][tid] + bsum[tid];
      float gf = pg[0][H + tid] + pg[1][H + tid] + bsum[H + tid];
      float gg = pg[0][2 * H + tid] + pg[1][2 * H + tid] + bsum[2 * H + tid];
      float go = pg[0][3 * H + tid] + pg[1][3 * H + tid] + bsum[3 * H + tid];
      gi = 1.0f / (1.0f + expf(-gi));
      gf = 1.0f / (1.0f + expf(-gf));
      gg = tanhf(gg);
      go = 1.0f / (1.0f + expf(-go));
      float c = gf * cs[tid] + gi * gg;
      cs[tid] = c;
      hs[tid] = go * tanhf(c);
    }
    __syncthreads();
    // --- P3: dt partials from LDS-staged W2T: k = tid&127, 32 h each --------
    if (tid < 512) {
      int k = tid & 127, part = tid >> 7;
      const int hbp = part * 32;
      float a = 0.f;
#pragma unroll 8
      for (int h = 0; h < 32; h += 4) {
        const float4 hv = *(const float4*)&hs[hbp + h];
        a += w2s[(hbp + h + 0) * H + k] * hv.x;
        a += w2s[(hbp + h + 1) * H + k] * hv.y;
        a += w2s[(hbp + h + 2) * H + k] * hv.z;
        a += w2s[(hbp + h + 3) * H + k] * hv.w;
      }
      pdt[part][k] = a;
    }
    __syncthreads();
    if (tid < 128) dt[tid] = pdt[0][tid] + pdt[1][tid] + pdt[2][tid] + pdt[3][tid];
    __syncthreads();
    // --- P4: score partials from REGISTERS: thread n = id, k = half*64..+63 -
    // er[kk] == encT2[b][kb+kk][n]; dt/vv broadcast via float4; accumulator
    // assignment (a0 = even k, a1 = odd k, ascending) bitwise == round 2.
    {
      const int kb = half * 64;
      float a0 = 0.f, a1 = 0.f;
#pragma unroll
      for (int k4 = 0; k4 < 64; k4 += 4) {
        const float4 dv = *(const float4*)&dt[kb + k4];
        const float4 vw = *(const float4*)&vv[kb + k4];
        a0 += vw.x * fast_tanh(er[k4 + 0] + dv.x);
        a1 += vw.y * fast_tanh(er[k4 + 1] + dv.y);
        a0 += vw.z * fast_tanh(er[k4 + 2] + dv.z);
        a1 += vw.w * fast_tanh(er[k4 + 3] + dv.w);
      }
      ps[half][id] = a0 + a1;
    }
    __syncthreads();
    // --- P5a: mask, gumbel, per-wave argmax + score max (waves 0..7) --------
    if (tid < 512) {
      float s = masked ? -INFINITY : (ps[0][tid] + ps[1][tid]);
      sc[tid] = s;
      uint32_t bits = gumbel_bits(keys.k[2 * t], keys.k[2 * t + 1], b * N + tid);
      // XLA uniform(minval=tiny, maxval=1): bits->[1,2)->-1, +tiny, max
      float f = __uint_as_float((bits >> 9) | 0x3f800000u) - 1.0f;
      float u = fmaxf(TINYF, f + TINYF);
      float g = -logf(-logf(u));  // accurate logf (hw log2 too sloppy near u~1)
      float z = s + g;
      int zi = tid;
      float m = s;
#pragma unroll
      for (int d = 32; d >= 1; d >>= 1) {
        float oz = __shfl_xor(z, d);
        int oi = __shfl_xor(zi, d);
        float om = __shfl_xor(m, d);
        if (oz > z || (oz == z && oi < zi)) { z = oz; zi = oi; }  // first-idx ties
        m = fmaxf(m, om);
      }
      if (lane == 0) { wr_z[wave] = z; wr_i[wave] = zi; wr_m[wave] = m; }
    }
    __syncthreads();
    // --- P5b: final argmax + max over the 8 waves ---------------------------
    if (tid == 0) {
      float bz = wr_z[0]; int bi = wr_i[0]; float bm = wr_m[0];
#pragma unroll
      for (int w = 1; w < 8; ++w) {
        if (wr_z[w] > bz || (wr_z[w] == bz && wr_i[w] < bi)) { bz = wr_z[w]; bi = wr_i[w]; }
        bm = fmaxf(bm, wr_m[w]);
      }
      s_idx = bi; s_smax = bm;
    }
    __syncthreads();
    // --- P6: softmax denom; mask update; next dec_input ---------------------
    if (tid < 512) {
      float e = expf(sc[tid] - s_smax);  // masked: exp(-inf) = 0
#pragma unroll
      for (int d = 32; d >= 1; d >>= 1) e += __shfl_xor(e, d);
      if (lane == 0) wr_s[wave] = e;
      if (tid == s_idx) masked = true;
    } else if (tid < 640) {
      xs[tid - 512] = enc[((size_t)b * N + s_idx) * H + (tid - 512)];
    }
    __syncthreads();
    // --- P6b: outputs (no barrier needed: writes global only) ---------------
    if (tid == 0) {
      float sum = wr_s[0] + wr_s[1] + wr_s[2] + wr_s[3]
                + wr_s[4] + wr_s[5] + wr_s[6] + wr_s[7];
      float p = expf(sc[s_idx] - s_smax) / sum;
      out[(size_t)b * T + t] = (float)s_idx;                       // tours [B,T]
      out[(size_t)B * T + (size_t)b * T + t] = logf(p + 1e-9f);    // log_probs
    }
    __syncthreads();
  }
}

// ---------------------------------------------------------------------------
extern "C" void kernel_launch(void* const* d_in, const int* in_sizes, int n_in,
                              void* d_out, int out_size, void* d_ws, size_t ws_size,
                              hipStream_t stream) {
  (void)in_sizes; (void)n_in; (void)out_size; (void)ws_size;
  const float* enc = (const float*)d_in[0];
  const float* Wih = (const float*)d_in[1];
  const float* Whh = (const float*)d_in[2];
  const float* bih = (const float*)d_in[3];
  const float* bhh = (const float*)d_in[4];
  const float* W1  = (const float*)d_in[5];
  const float* W2  = (const float*)d_in[6];
  const float* v   = (const float*)d_in[7];
  float* out = (float*)d_out;
  float* ws = (float*)d_ws;

  // ws layout (floats): WihT 65536 | WhhT 65536 | W2T 16384 | W1T 16384 | encT2 8388608
  float* WihT  = ws;
  float* WhhT  = ws + 65536;
  float* W2T   = ws + 131072;
  float* W1T   = ws + 147456;
  float* encT2 = ws + 163840;   // [b][k][n], ~33.5 MB

  KeyArgs keys = make_subkeys();  // pure host arithmetic: capture-safe

  // allow 128KB dynamic LDS for k_decode (host-side attr; capture-safe)
  static bool lds_attr_set = false;
  if (!lds_attr_set) {
    (void)hipFuncSetAttribute(reinterpret_cast<const void*>(k_decode),
                              hipFuncAttributeMaxDynamicSharedMemorySize, 131072);
    lds_attr_set = true;
  }

  k_transpose<<<640, 256, 0, stream>>>(Wih, Whh, W2, W1, WihT, WhhT, W2T, W1T);
  k_enc_trans<<<B * N / 16, 256, 0, stream>>>(enc, W1T, encT2);
  k_decode<<<B, 1024, 131072, stream>>>(enc, encT2, WihT, WhhT, W2T, bih, bhh, v, keys, out);
}

// Round 4
// 590.271 us; speedup vs baseline: 1.8247x; 1.7584x over previous
//
#include <hip/hip_runtime.h>
#include <cstdint>
#include <cstddef>

// ---------------------------------------------------------------------------
// Pointer-network decoder: B=128 batches decode T=32 steps over N=512 nodes.
// One block per batch (grid 128 <= 256 CUs: every block owns a full CU).
// Round 6: 512-thread block (flat-wg 512 -> default VGPR budget 128, vs the
// 1024-thread kernel where the backend pinned 64 and spilled er to scratch
// for 3 rounds straight, WRITE_SIZE 46MB). encT2[b] split: k=0..63 in 16
// NAMED float4 registers per thread (no alloca -> cannot be demoted), k=64..
// 127 in 128KB dynamic LDS. encT2 is read ONCE instead of per step. Each
// thread owns one n and one gate j -> full score in-register, ps[] split-K
// array + 2 barriers removed (9 -> 7 barriers/step), no idle threads in
// P5/P6. All accumulation orders preserved -> bit-identical (absmax 0.0).
// Sampling reproduces jax.random.categorical bit-exactly (threefry2x32).
// ---------------------------------------------------------------------------

constexpr int B = 128, N = 512, H = 128, T = 32;
constexpr int G4 = 4 * H;  // 512
constexpr float TINYF = 1.17549435e-38f;  // np.finfo(float32).tiny

// ---- JAX threefry2x32 block cipher (20 rounds) ----------------------------
__host__ __device__ inline uint32_t rotl32(uint32_t v, int d) {
  return (v << d) | (v >> (32 - d));
}

__host__ __device__ inline void tf2x32(uint32_t k0, uint32_t k1,
                                       uint32_t x0, uint32_t x1,
                                       uint32_t& o0, uint32_t& o1) {
  uint32_t ks2 = k0 ^ k1 ^ 0x1BD11BDAu;
  x0 += k0; x1 += k1;
#define TF_R(r) x0 += x1; x1 = rotl32(x1, (r)); x1 ^= x0;
  TF_R(13) TF_R(15) TF_R(26) TF_R(6)
  x0 += k1; x1 += ks2 + 1u;
  TF_R(17) TF_R(29) TF_R(16) TF_R(24)
  x0 += ks2; x1 += k0 + 2u;
  TF_R(13) TF_R(15) TF_R(26) TF_R(6)
  x0 += k0; x1 += k1 + 3u;
  TF_R(17) TF_R(29) TF_R(16) TF_R(24)
  x0 += k1; x1 += ks2 + 4u;
  TF_R(13) TF_R(15) TF_R(26) TF_R(6)
  x0 += ks2; x1 += k0 + 5u;
#undef TF_R
  o0 = x0; o1 = x1;
}

struct KeyArgs { uint32_t k[2 * T]; };  // per-step subkeys, 256 B by value

// Host-side key chain (partitionable split): key0 = (0,42);
// new_key = E_key(0,0), sub = E_key(0,1).
static KeyArgs make_subkeys() {
  KeyArgs ka;
  uint32_t k0 = 0u, k1 = 42u;
  for (int t = 0; t < T; ++t) {
    uint32_t n0, n1, s0, s1;
    tf2x32(k0, k1, 0u, 0u, n0, n1);
    tf2x32(k0, k1, 0u, 1u, s0, s1);
    ka.k[2 * t] = s0; ka.k[2 * t + 1] = s1;
    k0 = n0; k1 = n1;
  }
  return ka;
}

// 32-bit draw i (of 65536) for this step's subkey: w0^w1 of E_sub(0, i)
__device__ inline uint32_t gumbel_bits(uint32_t sk0, uint32_t sk1, int i) {
  uint32_t o0, o1;
  tf2x32(sk0, sk1, 0u, (uint32_t)i, o0, o1);
  return o0 ^ o1;
}

// fast tanh for the score hot loop; abs err ~2e-7 (clamp avoids inf/inf NaN)
__device__ inline float fast_tanh(float x) {
  float cx = fminf(9.0f, fmaxf(-9.0f, x));
  float t = __expf(2.0f * cx);
  return (t - 1.0f) * __builtin_amdgcn_rcpf(t + 1.0f);
}

// ---- setup kernel 1: transpose weights for coalesced access ---------------
__global__ void k_transpose(const float* __restrict__ Wih, const float* __restrict__ Whh,
                            const float* __restrict__ W2, const float* __restrict__ W1,
                            float* __restrict__ WihT, float* __restrict__ WhhT,
                            float* __restrict__ W2T, float* __restrict__ W1T) {
  int i = blockIdx.x * blockDim.x + threadIdx.x;
  if (i < H * G4) {
    int h = i >> 9, j = i & (G4 - 1);
    WihT[i] = Wih[j * H + h];
  } else if (i < 2 * H * G4) {
    int q = i - H * G4; int h = q >> 9, j = q & (G4 - 1);
    WhhT[q] = Whh[j * H + h];
  } else if (i < 2 * H * G4 + H * H) {
    int q = i - 2 * H * G4; int h = q >> 7, k = q & (H - 1);
    W2T[q] = W2[k * H + h];
  } else if (i < 2 * H * G4 + 2 * H * H) {
    int q = i - 2 * H * G4 - H * H; int h = q >> 7, k = q & (H - 1);
    W1T[q] = W1[k * H + h];
  }
}

// ---- setup kernel 2: encT2[b,k,n] = sum_h enc[b,n,h] * W1[k,h] ------------
// (k-major output for the decode score SGEMV). 16 enc rows staged in LDS;
// 256 threads = 128 k x 2 n-groups; per-thread 8 consecutive n -> 2x float4.
__global__ __launch_bounds__(256) void k_enc_trans(const float* __restrict__ enc,
                                                   const float* __restrict__ W1T,
                                                   float* __restrict__ encT2) {
  __shared__ __align__(16) float es[16 * 128];  // 8 KB
  int blk = blockIdx.x;
  int b = blk >> 5;               // 32 blocks per batch
  int n0 = (blk & 31) << 4;       // 16 rows
  const float* src = enc + ((size_t)b * N + n0) * H;
  for (int i = threadIdx.x; i < 16 * 128; i += 256) es[i] = src[i];
  __syncthreads();
  int k = threadIdx.x & 127, ng = threadIdx.x >> 7;
  float acc[8] = {0.f, 0.f, 0.f, 0.f, 0.f, 0.f, 0.f, 0.f};
  for (int h = 0; h < H; h += 4) {
    float w0 = W1T[(h + 0) * H + k];   // coalesced (lanes = consecutive k)
    float w1 = W1T[(h + 1) * H + k];
    float w2 = W1T[(h + 2) * H + k];
    float w3 = W1T[(h + 3) * H + k];
#pragma unroll
    for (int j = 0; j < 8; ++j) {
      const float4 e = *(const float4*)&es[(ng * 8 + j) * 128 + h];  // broadcast
      acc[j] += w0 * e.x + w1 * e.y + w2 * e.z + w3 * e.w;
    }
  }
  float* dst = encT2 + (size_t)b * H * N + (size_t)k * N + n0 + ng * 8;
  ((float4*)dst)[0] = make_float4(acc[0], acc[1], acc[2], acc[3]);
  ((float4*)dst)[1] = make_float4(acc[4], acc[5], acc[6], acc[7]);
}

#define REP16(M) M(0) M(1) M(2) M(3) M(4) M(5) M(6) M(7) \
                 M(8) M(9) M(10) M(11) M(12) M(13) M(14) M(15)

// ---- main fused decoder: 1 block per batch, 512 threads (8 waves) ---------
// Dynamic LDS (128 KB): e_lds[64][512] = encT2[b][64..127][:] (k-half 1).
// k-half 0 lives in 16 named float4 registers per thread (thread = node n).
__global__ __launch_bounds__(512)
__attribute__((amdgpu_waves_per_eu(2, 2))) void k_decode(
    const float* __restrict__ enc, const float* __restrict__ encT2,
    const float* __restrict__ WihT, const float* __restrict__ WhhT,
    const float* __restrict__ W2T,
    const float* __restrict__ bih, const float* __restrict__ bhh,
    const float* __restrict__ v,
    KeyArgs keys, float* __restrict__ out) {
  __shared__ __align__(16) float xs[H];     // dec_input
  __shared__ __align__(16) float hs[H];     // hx
  __shared__ __align__(16) float cs[H];     // cx
  __shared__ __align__(16) float dt[H];     // dec_trans = hx @ W2^T
  __shared__ __align__(16) float vv[H];
  __shared__ __align__(16) float bsum[G4];  // b_ih + b_hh
  __shared__ float pg[G4];                  // gate pre-activations (sans bias)
  __shared__ float pdt[4][H];               // dt partials (and init-mean partials)
  __shared__ float sc[N];                   // masked scores (P6b reads sc[s_idx])
  __shared__ float wr_z[8], wr_m[8], wr_s[8];
  __shared__ int wr_i[8];
  __shared__ float s_smax;
  __shared__ int s_idx;

  extern __shared__ __align__(16) float e_lds[];  // 64*512 floats = 128 KB

  const int tid = threadIdx.x;   // owns node n = tid and gate j = tid
  const int b = blockIdx.x;
  const int lane = tid & 63;
  const int wave = tid >> 6;     // 0..7

  // ---- register-stage encT2[b][0..63][tid]: 16 named float4 (no alloca) ---
  const float* ep = encT2 + (size_t)b * (H * N) + tid;
#define ERLD(i) float4 er##i = make_float4(ep[(size_t)(4*i+0) * N], \
                                           ep[(size_t)(4*i+1) * N], \
                                           ep[(size_t)(4*i+2) * N], \
                                           ep[(size_t)(4*i+3) * N]);
  REP16(ERLD)
#undef ERLD

  // ---- LDS-stage encT2[b][64..127][:] (128 KB), coalesced float4 ----------
  {
    const float4* src4 = (const float4*)(encT2 + (size_t)b * (H * N) + (size_t)64 * N);
    float4* dst4 = (float4*)e_lds;
#pragma unroll
    for (int i = 0; i < 16; ++i) dst4[tid + i * 512] = src4[tid + i * 512];
  }

  // ---- init: dec_input = mean_n enc[b,n,:]; h = c = 0 ----
  {
    int h = tid & 127, part = tid >> 7;
    float s = 0.f;
    const float* p = enc + ((size_t)b * N + part * 128) * H + h;
#pragma unroll 8
    for (int n = 0; n < 128; ++n) s += p[(size_t)n * H];  // coalesced across h
    pdt[part][h] = s;
    bsum[tid] = bih[tid] + bhh[tid];
  }
  if (tid < 128) { hs[tid] = 0.f; cs[tid] = 0.f; vv[tid] = v[tid]; }
  __syncthreads();
  if (tid < 128)
    xs[tid] = (pdt[0][tid] + pdt[1][tid] + pdt[2][tid] + pdt[3][tid]) * (1.0f / N);
  bool masked = false;  // thread tid owns node tid
  __syncthreads();

  for (int t = 0; t < T; ++t) {
    // --- P1: full gate j = tid. Per-half accumulators a0x/a0h (h 0..63) and
    // a1x/a1h (h 64..127), combined (a0x+a0h)+(a1x+a1h): bitwise == the old
    // split-K pg[0]+pg[1]. Wih/Whh stream from L2 (shared across blocks). ----
    {
      const float* wi = WihT + tid;
      const float* wh = WhhT + tid;
      float a0x = 0.f, a0h = 0.f, a1x = 0.f, a1h = 0.f;
#pragma unroll 8
      for (int h = 0; h < 64; h += 4) {
        const float4 xv = *(const float4*)&xs[h];
        a0x += wi[(size_t)(h + 0) * G4] * xv.x;
        a0x += wi[(size_t)(h + 1) * G4] * xv.y;
        a0x += wi[(size_t)(h + 2) * G4] * xv.z;
        a0x += wi[(size_t)(h + 3) * G4] * xv.w;
        const float4 hv = *(const float4*)&hs[h];
        a0h += wh[(size_t)(h + 0) * G4] * hv.x;
        a0h += wh[(size_t)(h + 1) * G4] * hv.y;
        a0h += wh[(size_t)(h + 2) * G4] * hv.z;
        a0h += wh[(size_t)(h + 3) * G4] * hv.w;
      }
#pragma unroll 8
      for (int h = 64; h < 128; h += 4) {
        const float4 xv = *(const float4*)&xs[h];
        a1x += wi[(size_t)(h + 0) * G4] * xv.x;
        a1x += wi[(size_t)(h + 1) * G4] * xv.y;
        a1x += wi[(size_t)(h + 2) * G4] * xv.z;
        a1x += wi[(size_t)(h + 3) * G4] * xv.w;
        const float4 hv = *(const float4*)&hs[h];
        a1h += wh[(size_t)(h + 0) * G4] * hv.x;
        a1h += wh[(size_t)(h + 1) * G4] * hv.y;
        a1h += wh[(size_t)(h + 2) * G4] * hv.z;
        a1h += wh[(size_t)(h + 3) * G4] * hv.w;
      }
      pg[tid] = (a0x + a0h) + (a1x + a1h);
    }
    __syncthreads();
    // --- P2: cell update (torch gate order i,f,g,o) -------------------------
    if (tid < 128) {
      float gi = pg[tid] + bsum[tid];
      float gf = pg[H + tid] + bsum[H + tid];
      float gg = pg[2 * H + tid] + bsum[2 * H + tid];
      float go = pg[3 * H + tid] + bsum[3 * H + tid];
      gi = 1.0f / (1.0f + expf(-gi));
      gf = 1.0f / (1.0f + expf(-gf));
      gg = tanhf(gg);
      go = 1.0f / (1.0f + expf(-go));
      float c = gf * cs[tid] + gi * gg;
      cs[tid] = c;
      hs[tid] = go * tanhf(c);
    }
    __syncthreads();
    // --- P3: dt partials: k = tid&127, 32 h each ----------------------------
    {
      int k = tid & 127, part = tid >> 7;
      const float* w2 = W2T + (size_t)(part * 32) * H + k;
      const int hbp = part * 32;
      float a = 0.f;
#pragma unroll 8
      for (int h = 0; h < 32; h += 4) {
        const float4 hv = *(const float4*)&hs[hbp + h];
        a += w2[(size_t)(h + 0) * H] * hv.x;
        a += w2[(size_t)(h + 1) * H] * hv.y;
        a += w2[(size_t)(h + 2) * H] * hv.z;
        a += w2[(size_t)(h + 3) * H] * hv.w;
      }
      pdt[part][k] = a;
    }
    __syncthreads();
    if (tid < 128) dt[tid] = pdt[0][tid] + pdt[1][tid] + pdt[2][tid] + pdt[3][tid];
    __syncthreads();
    // --- P4 + P5a fused: full score for node n = tid, then gumbel/argmax ----
    // k-half 0 from registers, k-half 1 from LDS; accumulator pattern
    // (a0 = k%4 in {0,2}, a1 = k%4 in {1,3}, ascending k, per half, then
    // (a0+a1) + (b0+b1)) is bitwise == the old ps[0]+ps[1].
    float s_score;
    {
      float a0 = 0.f, a1 = 0.f;
#define P4A(i) { const float4 dv = *(const float4*)&dt[4 * i];              \
                 const float4 vw = *(const float4*)&vv[4 * i];              \
                 a0 += vw.x * fast_tanh(er##i.x + dv.x);                    \
                 a1 += vw.y * fast_tanh(er##i.y + dv.y);                    \
                 a0 += vw.z * fast_tanh(er##i.z + dv.z);                    \
                 a1 += vw.w * fast_tanh(er##i.w + dv.w); }
      REP16(P4A)
#undef P4A
      float b0 = 0.f, b1 = 0.f;
#pragma unroll
      for (int k4 = 0; k4 < 64; k4 += 4) {
        const float e0 = e_lds[(k4 + 0) * N + tid];
        const float e1 = e_lds[(k4 + 1) * N + tid];
        const float e2 = e_lds[(k4 + 2) * N + tid];
        const float e3 = e_lds[(k4 + 3) * N + tid];
        const float4 dv = *(const float4*)&dt[64 + k4];
        const float4 vw = *(const float4*)&vv[64 + k4];
        b0 += vw.x * fast_tanh(e0 + dv.x);
        b1 += vw.y * fast_tanh(e1 + dv.y);
        b0 += vw.z * fast_tanh(e2 + dv.z);
        b1 += vw.w * fast_tanh(e3 + dv.w);
      }
      s_score = (a0 + a1) + (b0 + b1);
    }
    // P5a: mask, gumbel, per-wave argmax + score max (all 8 waves active)
    float s = masked ? -INFINITY : s_score;
    sc[tid] = s;
    {
      uint32_t bits = gumbel_bits(keys.k[2 * t], keys.k[2 * t + 1], b * N + tid);
      // XLA uniform(minval=tiny, maxval=1): bits->[1,2)->-1, +tiny, max
      float f = __uint_as_float((bits >> 9) | 0x3f800000u) - 1.0f;
      float u = fmaxf(TINYF, f + TINYF);
      float g = -logf(-logf(u));  // accurate logf (hw log2 too sloppy near u~1)
      float z = s + g;
      int zi = tid;
      float m = s;
#pragma unroll
      for (int d = 32; d >= 1; d >>= 1) {
        float oz = __shfl_xor(z, d);
        int oi = __shfl_xor(zi, d);
        float om = __shfl_xor(m, d);
        if (oz > z || (oz == z && oi < zi)) { z = oz; zi = oi; }  // first-idx ties
        m = fmaxf(m, om);
      }
      if (lane == 0) { wr_z[wave] = z; wr_i[wave] = zi; wr_m[wave] = m; }
    }
    __syncthreads();
    // --- P5b: final argmax + max over the 8 waves ---------------------------
    if (tid == 0) {
      float bz = wr_z[0]; int bi = wr_i[0]; float bm = wr_m[0];
#pragma unroll
      for (int w = 1; w < 8; ++w) {
        if (wr_z[w] > bz || (wr_z[w] == bz && wr_i[w] < bi)) { bz = wr_z[w]; bi = wr_i[w]; }
        bm = fmaxf(bm, wr_m[w]);
      }
      s_idx = bi; s_smax = bm;
    }
    __syncthreads();
    // --- P6: softmax denom; mask update; next dec_input ---------------------
    {
      float xnew = 0.f;
      if (tid < 128) xnew = enc[((size_t)b * N + s_idx) * H + tid];  // issue early
      float e = expf(s - s_smax);  // masked: exp(-inf) = 0
#pragma unroll
      for (int d = 32; d >= 1; d >>= 1) e += __shfl_xor(e, d);
      if (lane == 0) wr_s[wave] = e;
      if (tid == s_idx) masked = true;
      if (tid < 128) xs[tid] = xnew;
    }
    __syncthreads();
    // --- P6b: outputs (no barrier needed: writes global only) ---------------
    if (tid == 0) {
      float sum = wr_s[0] + wr_s[1] + wr_s[2] + wr_s[3]
                + wr_s[4] + wr_s[5] + wr_s[6] + wr_s[7];
      float p = expf(sc[s_idx] - s_smax) / sum;
      out[(size_t)b * T + t] = (float)s_idx;                       // tours [B,T]
      out[(size_t)B * T + (size_t)b * T + t] = logf(p + 1e-9f);    // log_probs
    }
    __syncthreads();
  }
}

// ---------------------------------------------------------------------------
extern "C" void kernel_launch(void* const* d_in, const int* in_sizes, int n_in,
                              void* d_out, int out_size, void* d_ws, size_t ws_size,
                              hipStream_t stream) {
  (void)in_sizes; (void)n_in; (void)out_size; (void)ws_size;
  const float* enc = (const float*)d_in[0];
  const float* Wih = (const float*)d_in[1];
  const float* Whh = (const float*)d_in[2];
  const float* bih = (const float*)d_in[3];
  const float* bhh = (const float*)d_in[4];
  const float* W1  = (const float*)d_in[5];
  const float* W2  = (const float*)d_in[6];
  const float* v   = (const float*)d_in[7];
  float* out = (float*)d_out;
  float* ws = (float*)d_ws;

  // ws layout (floats): WihT 65536 | WhhT 65536 | W2T 16384 | W1T 16384 | encT2 8388608
  float* WihT  = ws;
  float* WhhT  = ws + 65536;
  float* W2T   = ws + 131072;
  float* W1T   = ws + 147456;
  float* encT2 = ws + 163840;   // [b][k][n], ~33.5 MB

  KeyArgs keys = make_subkeys();  // pure host arithmetic: capture-safe

  // allow 128KB dynamic LDS for k_decode (host-side attr; capture-safe)
  static bool lds_attr_set = false;
  if (!lds_attr_set) {
    (void)hipFuncSetAttribute(reinterpret_cast<const void*>(k_decode),
                              hipFuncAttributeMaxDynamicSharedMemorySize, 131072);
    lds_attr_set = true;
  }

  k_transpose<<<640, 256, 0, stream>>>(Wih, Whh, W2, W1, WihT, WhhT, W2T, W1T);
  k_enc_trans<<<B * N / 16, 256, 0, stream>>>(enc, W1T, encT2);
  k_decode<<<B, 512, 131072, stream>>>(enc, encT2, WihT, WhhT, W2T, bih, bhh, v, keys, out);
}